// Round 4
// baseline (610.517 us; speedup 1.0000x reference)
//
#include <hip/hip_runtime.h>
#include <math.h>

static constexpr int E = 100000;   // edges (segments)
static constexpr int M = 1000000;  // edge-edge pairs
static constexpr int NBE = (E + 255) / 256;   // 391
static constexpr int NBM = (M + 255) / 256;   // 3907
static constexpr int NBP = (E + 63) / 64;     // 1563 proj blocks

// ---------------- workspace layout (bytes) ----------------
#define O_FLAG   0
#define O_WEFF   512
#define O_BKEFF  4608
#define O_BSWZ   5120        // 32768 B
#define O_COUNTS 38400       // E ints
#define O_OFFS   438784      // E ints
#define O_BSUM   838784      // 391 ints (pad 2048)
#define O_BSUM2  840832      // 512 ints
#define O_BINOFF 842880      // 256 ints
#define O_BCUR   843904      // 256 ints
#define O_BHIST  844928      // 391*256 ints = 400384 B
#define O_ORDER  1245312     // E ints
#define O_POS    1645312     // M ints
#define O_CSR    5645312     // M ints
#define O_KS     9645312     // E*8 f32
#define O_VH     12845312    // E*128 bf16 = 25600000 B
#define WS_NEEDED (O_VH + (size_t)E * 128 * 2)

typedef float f32x4 __attribute__((ext_vector_type(4)));
typedef short s16x8 __attribute__((ext_vector_type(8)));

__device__ __forceinline__ unsigned short f2bf(float f) {
    unsigned u = __float_as_uint(f);
    u += 0x7fffu + ((u >> 16) & 1u);
    return (unsigned short)(u >> 16);
}
__device__ __forceinline__ float bflo(unsigned u) { return __uint_as_float(u << 16); }
__device__ __forceinline__ float bfhi(unsigned u) { return __uint_as_float(u & 0xffff0000u); }

// prep: zero counts | weff/bkeff fold | dtype detect | Wv -> MFMA-B bf16 swizzle
__global__ void k_prep(const float* __restrict__ Wk, const float* __restrict__ bk,
                       const float* __restrict__ Aw, const float* __restrict__ Wv,
                       const int* __restrict__ idx32, int* __restrict__ counts,
                       int* __restrict__ flag, float* __restrict__ weff,
                       float* __restrict__ bkeff, unsigned short* __restrict__ Bswz) {
    int bid = blockIdx.x, t = threadIdx.x;
    if (bid < NBE) {
        int i = bid * 256 + t;
        if (i < E) counts[i] = 0;
        return;
    }
    if (bid == NBE) {
        if (t < 128) {
            for (int h = 0; h < 8; h++) {
                float s = 0.f;
                for (int d = 0; d < 16; d++) s += Wk[t * 128 + h * 16 + d] * Aw[d * 8 + h];
                weff[t * 8 + h] = s;
            }
            if (t < 8) {
                float s = 0.f;
                for (int d = 0; d < 16; d++) s += bk[t * 16 + d] * Aw[d * 8 + t];
                bkeff[t] = s;
            }
        }
        return;
    }
    if (bid == NBE + 1) {
        if (t == 0) {
            int z = 0;
            for (int i = 0; i < 64; i++) z += (idx32[2 * i + 1] == 0) ? 1 : 0;
            *flag = (z == 64) ? 1 : 0;
        }
        return;
    }
    int p = (bid - (NBE + 2)) * 256 + t;     // f*64+lane
    int f = p >> 6, lane = p & 63;
    int c = f >> 3, tt = f & 7;
    int quad = lane >> 4, nn = lane & 15;
#pragma unroll
    for (int j = 0; j < 8; j++) {
        int k = c * 32 + quad * 8 + j;
        Bswz[p * 8 + j] = f2bf(Wv[k * 128 + tt * 16 + nn]);
    }
}

// Fused: count+rank atomic pass (5/7 of blocks) interleaved with MFMA projection
// (2/7 of blocks) so streaming/MFMA work overlaps far-atomic latency.
__global__ __launch_bounds__(256) void k_cp(
    const void* __restrict__ idx, const int* __restrict__ flagp,
    int* __restrict__ counts, int* __restrict__ pos,
    const float* __restrict__ A, const short* __restrict__ Bswz,
    const float* __restrict__ bv, const float* __restrict__ weff,
    const float* __restrict__ bkeff, unsigned short* __restrict__ Vh,
    float* __restrict__ ksb) {
    int bid = blockIdx.x, t = threadIdx.x;
    int r = bid % 7;
    if (r < 5) {
        int cid = (bid / 7) * 5 + r;
        if (cid >= NBM) return;
        int m = cid * 256 + t;
        if (m >= M) return;
        int d = (*flagp) ? (int)((const long long*)idx)[M + m] : ((const int*)idx)[M + m];
        pos[m] = atomicAdd(&counts[d], 1);
        return;
    }
    int pid = (bid / 7) * 2 + (r - 5);
    if (pid >= NBP) return;

    __shared__ float we[1024];
    ((float4*)we)[t] = ((const float4*)weff)[t & 255];
    __syncthreads();

    int lane = t & 63, wid = t >> 6;
    int rowbase = pid * 64 + wid * 16;
    int quad = lane >> 4, nn = lane & 15;
    int m = rowbase + nn;
    int mc = (m < E) ? m : (E - 1);

    f32x4 acc[8];
#pragma unroll
    for (int tt = 0; tt < 8; tt++) acc[tt] = (f32x4){0.f, 0.f, 0.f, 0.f};
    float p[8];
#pragma unroll
    for (int h = 0; h < 8; h++) p[h] = 0.f;

#pragma unroll
    for (int c = 0; c < 4; c++) {
        const float4* ap = (const float4*)(A + (size_t)mc * 128 + c * 32 + quad * 8);
        float4 f0 = ap[0], f1 = ap[1];
        float a[8] = {f0.x, f0.y, f0.z, f0.w, f1.x, f1.y, f1.z, f1.w};
#pragma unroll
        for (int j = 0; j < 8; j++) {
            int k = c * 32 + quad * 8 + j;
            float4 w0 = *(const float4*)&we[k * 8];
            float4 w1 = *(const float4*)&we[k * 8 + 4];
            p[0] += a[j] * w0.x; p[1] += a[j] * w0.y;
            p[2] += a[j] * w0.z; p[3] += a[j] * w0.w;
            p[4] += a[j] * w1.x; p[5] += a[j] * w1.y;
            p[6] += a[j] * w1.z; p[7] += a[j] * w1.w;
        }
        s16x8 afrag;
#pragma unroll
        for (int j = 0; j < 8; j++) afrag[j] = (short)f2bf(a[j]);
#pragma unroll
        for (int tt = 0; tt < 8; tt++) {
            s16x8 bfrag = *(const s16x8*)(Bswz + (((c * 8 + tt) * 64 + lane) << 3));
            acc[tt] = __builtin_amdgcn_mfma_f32_16x16x32_bf16(afrag, bfrag, acc[tt], 0, 0, 0);
        }
    }
#pragma unroll
    for (int off = 16; off <= 32; off <<= 1)
#pragma unroll
        for (int h = 0; h < 8; h++) p[h] += __shfl_xor(p[h], off, 64);
    if (quad == 0 && m < E) {
        float4* op = (float4*)(ksb + (size_t)m * 8);
        op[0] = make_float4(p[0] + bkeff[0], p[1] + bkeff[1], p[2] + bkeff[2], p[3] + bkeff[3]);
        op[1] = make_float4(p[4] + bkeff[4], p[5] + bkeff[5], p[6] + bkeff[6], p[7] + bkeff[7]);
    }
#pragma unroll
    for (int tt = 0; tt < 8; tt++) {
        float bvc = bv[tt * 16 + nn];
#pragma unroll
        for (int rr = 0; rr < 4; rr++) {
            int row = rowbase + quad * 4 + rr;
            if (row < E)
                Vh[(size_t)row * 128 + tt * 16 + nn] = f2bf(acc[tt][rr] + bvc);
        }
    }
}

// scanA: per-256-block exclusive scan of counts + per-block 256-bin length histogram
__global__ void k_scanA(const int* __restrict__ counts, int* __restrict__ offs,
                        int* __restrict__ bsum, int* __restrict__ bhist) {
    __shared__ int sm[256];
    __shared__ int hist[256];
    int tid = threadIdx.x;
    int i = blockIdx.x * 256 + tid;
    int v = (i < E) ? counts[i] : 0;
    hist[tid] = 0;
    sm[tid] = v;
    __syncthreads();
    if (i < E) atomicAdd(&hist[v > 255 ? 255 : v], 1);
    for (int off = 1; off < 256; off <<= 1) {
        int add = (tid >= off) ? sm[tid - off] : 0;
        __syncthreads();
        sm[tid] += add;
        __syncthreads();
    }
    if (i < E) offs[i] = sm[tid] - v;
    if (tid == 255) bsum[blockIdx.x] = sm[255];
    bhist[blockIdx.x * 256 + tid] = hist[tid];
}

// scanB: scan block sums; reduce bin histogram columns; descending-n bin offsets
__global__ void k_scanB(const int* __restrict__ bsum, const int* __restrict__ bhist,
                        int* __restrict__ bsum2, int* __restrict__ binoff,
                        int* __restrict__ bcur, int nb) {
    __shared__ int sm[512];
    __shared__ int bt[256];
    __shared__ int s2[256];
    int tid = threadIdx.x;
    int v = (tid < nb) ? bsum[tid] : 0;
    sm[tid] = v;
    __syncthreads();
    for (int off = 1; off < 512; off <<= 1) {
        int add = (tid >= off) ? sm[tid - off] : 0;
        __syncthreads();
        sm[tid] += add;
        __syncthreads();
    }
    bsum2[tid] = sm[tid] - v;
    if (tid < 256) {
        int s = 0;
        for (int j = 0; j < nb; j++) s += bhist[j * 256 + tid];
        bt[tid] = s;
    }
    __syncthreads();
    if (tid < 256) s2[tid] = bt[255 - tid];
    __syncthreads();
    for (int off = 1; off < 256; off <<= 1) {
        int add = (tid < 256 && tid >= off) ? s2[tid - off] : 0;
        __syncthreads();
        if (tid < 256) s2[tid] += add;
        __syncthreads();
    }
    if (tid < 256) {
        binoff[tid] = s2[255 - tid] - bt[tid];  // sum of bt[b'] for b' > tid
        bcur[tid] = 0;
    }
}

// Fused: atomic-free CSR fill + segment-order scatter (grouped by n, descending)
__global__ void k_fill(const void* __restrict__ idx, const int* __restrict__ flagp,
                       const int* __restrict__ offs, const int* __restrict__ bsum2,
                       const int* __restrict__ pos, int* __restrict__ csr,
                       const int* __restrict__ counts, const int* __restrict__ binoff,
                       int* __restrict__ bcur, int* __restrict__ order) {
    int bid = blockIdx.x, t = threadIdx.x;
    if (bid < NBM) {
        int m = bid * 256 + t;
        if (m >= M) return;
        int s, d;
        if (*flagp) {
            const long long* p = (const long long*)idx;
            s = (int)p[m]; d = (int)p[M + m];
        } else {
            const int* p = (const int*)idx;
            s = p[m]; d = p[M + m];
        }
        csr[offs[d] + bsum2[d >> 8] + pos[m]] = s;
        return;
    }
    int i = (bid - NBM) * 256 + t;
    if (i >= E) return;
    int n = counts[i];
    if (n > 255) n = 255;
    int r = atomicAdd(&bcur[n], 1);
    order[binoff[n] + r] = i;
}

// One lane per (segment, head); segments grouped by identical n (via order[]).
// Online softmax, 4-deep rotating prefetch: csr 8 ahead, ks+Vh rows 4 ahead.
#define ROWL(p, sidx, cond) \
    if (cond) { \
        k##p = ksb[(size_t)(sidx) * 8 + h]; \
        const uint4* vp_ = (const uint4*)(Vh + (size_t)(sidx) * 128 + (h << 4)); \
        a##p = vp_[0]; b##p = vp_[1]; \
    }

#define CONS(kk, aa, bb) { \
    float kv_ = kk; \
    float w_; \
    if (kv_ > mx) { \
        float r_ = __expf(mx - kv_); \
        l *= r_; \
        _Pragma("unroll") for (int j_ = 0; j_ < 16; j_++) acc[j_] *= r_; \
        mx = kv_; w_ = 1.f; \
    } else w_ = __expf(kv_ - mx); \
    l += w_; \
    acc[0]  += bflo(aa.x) * w_; acc[1]  += bfhi(aa.x) * w_; \
    acc[2]  += bflo(aa.y) * w_; acc[3]  += bfhi(aa.y) * w_; \
    acc[4]  += bflo(aa.z) * w_; acc[5]  += bfhi(aa.z) * w_; \
    acc[6]  += bflo(aa.w) * w_; acc[7]  += bfhi(aa.w) * w_; \
    acc[8]  += bflo(bb.x) * w_; acc[9]  += bfhi(bb.x) * w_; \
    acc[10] += bflo(bb.y) * w_; acc[11] += bfhi(bb.y) * w_; \
    acc[12] += bflo(bb.z) * w_; acc[13] += bfhi(bb.z) * w_; \
    acc[14] += bflo(bb.w) * w_; acc[15] += bfhi(bb.w) * w_; \
}

__global__ __launch_bounds__(256) void k_seg(
    const float* __restrict__ ksb, const unsigned short* __restrict__ Vh,
    const int* __restrict__ offs, const int* __restrict__ bsum2,
    const int* __restrict__ csr, const int* __restrict__ order,
    float* __restrict__ out) {
    int t = threadIdx.x;
    int h = t & 7;
    int g = blockIdx.x * 32 + (t >> 3);            // grid 3125*32 = E
    int seg = order[g];
    int beg = offs[seg] + bsum2[seg >> 8];
    int end = (seg + 1 < E) ? (offs[seg + 1] + bsum2[(seg + 1) >> 8]) : M;
    int n = end - beg;

    float acc[16];
#pragma unroll
    for (int j = 0; j < 16; j++) acc[j] = 0.f;
    float l = 0.f, mx = -INFINITY;

    if (n > 0) {
        int s0 = 0, s1 = 0, s2 = 0, s3 = 0, t0 = 0, t1 = 0, t2 = 0, t3 = 0;
        float k0 = 0, k1 = 0, k2 = 0, k3 = 0;
        uint4 a0 = {}, b0 = {}, a1 = {}, b1 = {}, a2 = {}, b2 = {}, a3 = {}, b3 = {};
        s0 = csr[beg];
        if (n > 1) s1 = csr[beg + 1];
        if (n > 2) s2 = csr[beg + 2];
        if (n > 3) s3 = csr[beg + 3];
        ROWL(0, s0, true)
        ROWL(1, s1, n > 1)
        ROWL(2, s2, n > 2)
        ROWL(3, s3, n > 3)
        if (n > 4) t0 = csr[beg + 4];
        if (n > 5) t1 = csr[beg + 5];
        if (n > 6) t2 = csr[beg + 6];
        if (n > 7) t3 = csr[beg + 7];
        int i = 0;
        while (i + 4 <= n) {
            CONS(k0, a0, b0) ROWL(0, t0, i + 4 < n) if (i + 8 < n)  t0 = csr[beg + i + 8];
            CONS(k1, a1, b1) ROWL(1, t1, i + 5 < n) if (i + 9 < n)  t1 = csr[beg + i + 9];
            CONS(k2, a2, b2) ROWL(2, t2, i + 6 < n) if (i + 10 < n) t2 = csr[beg + i + 10];
            CONS(k3, a3, b3) ROWL(3, t3, i + 7 < n) if (i + 11 < n) t3 = csr[beg + i + 11];
            i += 4;
        }
        if (i < n) { CONS(k0, a0, b0) i++; }
        if (i < n) { CONS(k1, a1, b1) i++; }
        if (i < n) { CONS(k2, a2, b2) }
    }
    float inv = 1.0f / (l + 1e-16f);
    float4* op = (float4*)(out + (size_t)seg * 128 + h * 16);
#pragma unroll
    for (int j = 0; j < 4; j++)
        op[j] = make_float4(acc[4 * j] * inv, acc[4 * j + 1] * inv,
                            acc[4 * j + 2] * inv, acc[4 * j + 3] * inv);
}

extern "C" void kernel_launch(void* const* d_in, const int* in_sizes, int n_in,
                              void* d_out, int out_size, void* d_ws, size_t ws_size,
                              hipStream_t stream) {
    const float* edge_attr = (const float*)d_in[0];
    const void*  eei       = d_in[1];
    // d_in[2]=Wq, d_in[3]=bq -- dead: Q cancels in the segment softmax
    const float* Wk = (const float*)d_in[4];
    const float* bk = (const float*)d_in[5];
    const float* Wv = (const float*)d_in[6];
    const float* bv = (const float*)d_in[7];
    const float* Aw = (const float*)d_in[8];
    float* out = (float*)d_out;

    if (ws_size < WS_NEEDED) return;

    char* ws = (char*)d_ws;
    int*   flag   = (int*)(ws + O_FLAG);
    float* weff   = (float*)(ws + O_WEFF);
    float* bkeff  = (float*)(ws + O_BKEFF);
    unsigned short* Bswz = (unsigned short*)(ws + O_BSWZ);
    int*   counts = (int*)(ws + O_COUNTS);
    int*   offs   = (int*)(ws + O_OFFS);
    int*   bsum   = (int*)(ws + O_BSUM);
    int*   bsum2  = (int*)(ws + O_BSUM2);
    int*   binoff = (int*)(ws + O_BINOFF);
    int*   bcur   = (int*)(ws + O_BCUR);
    int*   bhist  = (int*)(ws + O_BHIST);
    int*   order  = (int*)(ws + O_ORDER);
    int*   pos    = (int*)(ws + O_POS);
    int*   csr    = (int*)(ws + O_CSR);
    float* ksb    = (float*)(ws + O_KS);
    unsigned short* Vh = (unsigned short*)(ws + O_VH);

    k_prep<<<NBE + 10, 256, 0, stream>>>(Wk, bk, Aw, Wv, (const int*)eei,
                                         counts, flag, weff, bkeff, Bswz);
    k_cp<<<7 * 782, 256, 0, stream>>>(eei, flag, counts, pos, edge_attr,
                                      (const short*)Bswz, bv, weff, bkeff, Vh, ksb);
    k_scanA<<<NBE, 256, 0, stream>>>(counts, offs, bsum, bhist);
    k_scanB<<<1, 512, 0, stream>>>(bsum, bhist, bsum2, binoff, bcur, NBE);
    k_fill<<<NBM + NBE, 256, 0, stream>>>(eei, flag, offs, bsum2, pos, csr,
                                          counts, binoff, bcur, order);
    k_seg<<<E / 32, 256, 0, stream>>>(ksb, Vh, offs, bsum2, csr, order, out);
}

// Round 5
// 338.764 us; speedup vs baseline: 1.8022x; 1.8022x over previous
//
#include <hip/hip_runtime.h>
#include <math.h>

static constexpr int E = 100000;   // edges (segments)
static constexpr int M = 1000000;  // edge-edge pairs
static constexpr int NBE = (E + 255) / 256;   // 391
static constexpr int NBM = (M + 255) / 256;   // 3907
static constexpr int NBP = (E + 63) / 64;     // 1563 proj blocks

// ---------------- workspace layout (bytes) ----------------
#define O_FLAG   0
#define O_WEFF   512
#define O_BKEFF  4608
#define O_BSWZ   5120        // 32768 B
#define O_COUNTS 38400       // E ints
#define O_OFFS   438784      // E ints
#define O_BSUM   838784      // 391 ints (pad 2048)
#define O_BSUM2  840832      // 512 ints
#define O_BINOFF 842880      // 256 ints
#define O_BCUR   843904      // 256 ints (unused now, kept for layout stability)
#define O_BHIST  844928      // 391*256 ints = 400384 B
#define O_ORDER  1245312     // E ints
#define O_POS    1645312     // M ints
#define O_CSR    5645312     // M ints
#define O_KS     9645312     // E*8 f32
#define O_VH     12845312    // E*128 bf16 = 25600000 B
#define WS_NEEDED (O_VH + (size_t)E * 128 * 2)

typedef float f32x4 __attribute__((ext_vector_type(4)));
typedef short s16x8 __attribute__((ext_vector_type(8)));

__device__ __forceinline__ unsigned short f2bf(float f) {
    unsigned u = __float_as_uint(f);
    u += 0x7fffu + ((u >> 16) & 1u);
    return (unsigned short)(u >> 16);
}
__device__ __forceinline__ float bflo(unsigned u) { return __uint_as_float(u << 16); }
__device__ __forceinline__ float bfhi(unsigned u) { return __uint_as_float(u & 0xffff0000u); }

// prep: zero counts | weff/bkeff fold | dtype detect | Wv -> MFMA-B bf16 swizzle
__global__ void k_prep(const float* __restrict__ Wk, const float* __restrict__ bk,
                       const float* __restrict__ Aw, const float* __restrict__ Wv,
                       const int* __restrict__ idx32, int* __restrict__ counts,
                       int* __restrict__ flag, float* __restrict__ weff,
                       float* __restrict__ bkeff, unsigned short* __restrict__ Bswz) {
    int bid = blockIdx.x, t = threadIdx.x;
    if (bid < NBE) {
        int i = bid * 256 + t;
        if (i < E) counts[i] = 0;
        return;
    }
    if (bid == NBE) {
        if (t < 128) {
            for (int h = 0; h < 8; h++) {
                float s = 0.f;
                for (int d = 0; d < 16; d++) s += Wk[t * 128 + h * 16 + d] * Aw[d * 8 + h];
                weff[t * 8 + h] = s;
            }
            if (t < 8) {
                float s = 0.f;
                for (int d = 0; d < 16; d++) s += bk[t * 16 + d] * Aw[d * 8 + t];
                bkeff[t] = s;
            }
        }
        return;
    }
    if (bid == NBE + 1) {
        if (t == 0) {
            int z = 0;
            for (int i = 0; i < 64; i++) z += (idx32[2 * i + 1] == 0) ? 1 : 0;
            *flag = (z == 64) ? 1 : 0;
        }
        return;
    }
    int p = (bid - (NBE + 2)) * 256 + t;     // f*64+lane
    int f = p >> 6, lane = p & 63;
    int c = f >> 3, tt = f & 7;
    int quad = lane >> 4, nn = lane & 15;
#pragma unroll
    for (int j = 0; j < 8; j++) {
        int k = c * 32 + quad * 8 + j;
        Bswz[p * 8 + j] = f2bf(Wv[k * 128 + tt * 16 + nn]);
    }
}

// Fused: count+rank atomic pass (5/7 of blocks) interleaved with MFMA projection
// (2/7 of blocks) so streaming/MFMA work overlaps far-atomic latency.
__global__ __launch_bounds__(256) void k_cp(
    const void* __restrict__ idx, const int* __restrict__ flagp,
    int* __restrict__ counts, int* __restrict__ pos,
    const float* __restrict__ A, const short* __restrict__ Bswz,
    const float* __restrict__ bv, const float* __restrict__ weff,
    const float* __restrict__ bkeff, unsigned short* __restrict__ Vh,
    float* __restrict__ ksb) {
    int bid = blockIdx.x, t = threadIdx.x;
    int r = bid % 7;
    if (r < 5) {
        int cid = (bid / 7) * 5 + r;
        if (cid >= NBM) return;
        int m = cid * 256 + t;
        if (m >= M) return;
        int d = (*flagp) ? (int)((const long long*)idx)[M + m] : ((const int*)idx)[M + m];
        pos[m] = atomicAdd(&counts[d], 1);
        return;
    }
    int pid = (bid / 7) * 2 + (r - 5);
    if (pid >= NBP) return;

    __shared__ float we[1024];
    ((float4*)we)[t] = ((const float4*)weff)[t & 255];
    __syncthreads();

    int lane = t & 63, wid = t >> 6;
    int rowbase = pid * 64 + wid * 16;
    int quad = lane >> 4, nn = lane & 15;
    int m = rowbase + nn;
    int mc = (m < E) ? m : (E - 1);

    f32x4 acc[8];
#pragma unroll
    for (int tt = 0; tt < 8; tt++) acc[tt] = (f32x4){0.f, 0.f, 0.f, 0.f};
    float p[8];
#pragma unroll
    for (int h = 0; h < 8; h++) p[h] = 0.f;

#pragma unroll
    for (int c = 0; c < 4; c++) {
        const float4* ap = (const float4*)(A + (size_t)mc * 128 + c * 32 + quad * 8);
        float4 f0 = ap[0], f1 = ap[1];
        float a[8] = {f0.x, f0.y, f0.z, f0.w, f1.x, f1.y, f1.z, f1.w};
#pragma unroll
        for (int j = 0; j < 8; j++) {
            int k = c * 32 + quad * 8 + j;
            float4 w0 = *(const float4*)&we[k * 8];
            float4 w1 = *(const float4*)&we[k * 8 + 4];
            p[0] += a[j] * w0.x; p[1] += a[j] * w0.y;
            p[2] += a[j] * w0.z; p[3] += a[j] * w0.w;
            p[4] += a[j] * w1.x; p[5] += a[j] * w1.y;
            p[6] += a[j] * w1.z; p[7] += a[j] * w1.w;
        }
        s16x8 afrag;
#pragma unroll
        for (int j = 0; j < 8; j++) afrag[j] = (short)f2bf(a[j]);
#pragma unroll
        for (int tt = 0; tt < 8; tt++) {
            s16x8 bfrag = *(const s16x8*)(Bswz + (((c * 8 + tt) * 64 + lane) << 3));
            acc[tt] = __builtin_amdgcn_mfma_f32_16x16x32_bf16(afrag, bfrag, acc[tt], 0, 0, 0);
        }
    }
#pragma unroll
    for (int off = 16; off <= 32; off <<= 1)
#pragma unroll
        for (int h = 0; h < 8; h++) p[h] += __shfl_xor(p[h], off, 64);
    if (quad == 0 && m < E) {
        float4* op = (float4*)(ksb + (size_t)m * 8);
        op[0] = make_float4(p[0] + bkeff[0], p[1] + bkeff[1], p[2] + bkeff[2], p[3] + bkeff[3]);
        op[1] = make_float4(p[4] + bkeff[4], p[5] + bkeff[5], p[6] + bkeff[6], p[7] + bkeff[7]);
    }
#pragma unroll
    for (int tt = 0; tt < 8; tt++) {
        float bvc = bv[tt * 16 + nn];
#pragma unroll
        for (int rr = 0; rr < 4; rr++) {
            int row = rowbase + quad * 4 + rr;
            if (row < E)
                Vh[(size_t)row * 128 + tt * 16 + nn] = f2bf(acc[tt][rr] + bvc);
        }
    }
}

// scanA: per-256-block exclusive scan of counts + per-block 256-bin length histogram
__global__ void k_scanA(const int* __restrict__ counts, int* __restrict__ offs,
                        int* __restrict__ bsum, int* __restrict__ bhist) {
    __shared__ int sm[256];
    __shared__ int hist[256];
    int tid = threadIdx.x;
    int i = blockIdx.x * 256 + tid;
    int v = (i < E) ? counts[i] : 0;
    hist[tid] = 0;
    sm[tid] = v;
    __syncthreads();
    if (i < E) atomicAdd(&hist[v > 255 ? 255 : v], 1);
    for (int off = 1; off < 256; off <<= 1) {
        int add = (tid >= off) ? sm[tid - off] : 0;
        __syncthreads();
        sm[tid] += add;
        __syncthreads();
    }
    if (i < E) offs[i] = sm[tid] - v;
    if (tid == 255) bsum[blockIdx.x] = sm[255];
    bhist[blockIdx.x * 256 + tid] = hist[tid];
}

// scanB: scan block sums; convert bhist columns to exclusive per-block prefixes
// (bin bases); descending-n bin offsets. Zero global atomics downstream.
__global__ void k_scanB(const int* __restrict__ bsum, int* __restrict__ bhist,
                        int* __restrict__ bsum2, int* __restrict__ binoff, int nb) {
    __shared__ int sm[512];
    __shared__ int bt[256];
    __shared__ int s2[256];
    int tid = threadIdx.x;
    int v = (tid < nb) ? bsum[tid] : 0;
    sm[tid] = v;
    __syncthreads();
    for (int off = 1; off < 512; off <<= 1) {
        int add = (tid >= off) ? sm[tid - off] : 0;
        __syncthreads();
        sm[tid] += add;
        __syncthreads();
    }
    bsum2[tid] = sm[tid] - v;
    if (tid < 256) {
        // column tid of bhist: exclusive prefix along blocks; total -> bt
        int run = 0;
        for (int j = 0; j < nb; j++) {
            int tmp = bhist[j * 256 + tid];
            bhist[j * 256 + tid] = run;
            run += tmp;
        }
        bt[tid] = run;
    }
    __syncthreads();
    if (tid < 256) s2[tid] = bt[255 - tid];
    __syncthreads();
    for (int off = 1; off < 256; off <<= 1) {
        int add = (tid < 256 && tid >= off) ? s2[tid - off] : 0;
        __syncthreads();
        if (tid < 256) s2[tid] += add;
        __syncthreads();
    }
    if (tid < 256) binoff[tid] = s2[255 - tid] - bt[tid];  // sum of bt[b'>tid]
}

// Fused: atomic-free CSR fill + order scatter (grouped by n desc, LDS-rank only)
__global__ void k_fill(const void* __restrict__ idx, const int* __restrict__ flagp,
                       const int* __restrict__ offs, const int* __restrict__ bsum2,
                       const int* __restrict__ pos, int* __restrict__ csr,
                       const int* __restrict__ counts, const int* __restrict__ binoff,
                       const int* __restrict__ bhist, int* __restrict__ order) {
    int bid = blockIdx.x, t = threadIdx.x;
    if (bid < NBM) {
        int m = bid * 256 + t;
        if (m >= M) return;
        int s, d;
        if (*flagp) {
            const long long* p = (const long long*)idx;
            s = (int)p[m]; d = (int)p[M + m];
        } else {
            const int* p = (const int*)idx;
            s = p[m]; d = p[M + m];
        }
        csr[offs[d] + bsum2[d >> 8] + pos[m]] = s;
        return;
    }
    __shared__ int lh[256];
    int blk = bid - NBM;
    int i = blk * 256 + t;
    lh[t] = 0;
    __syncthreads();
    if (i >= E) return;
    int n = counts[i];
    if (n > 255) n = 255;
    int lr = atomicAdd(&lh[n], 1);            // LDS atomic: intra-block rank
    order[binoff[n] + bhist[blk * 256 + n] + lr] = i;
}

// One lane per (segment, head); segments grouped by identical n (via order[]).
// Online softmax, 4-deep rotating prefetch: csr 8 ahead, ks+Vh rows 4 ahead.
#define ROWL(p, sidx, cond) \
    if (cond) { \
        k##p = ksb[(size_t)(sidx) * 8 + h]; \
        const uint4* vp_ = (const uint4*)(Vh + (size_t)(sidx) * 128 + (h << 4)); \
        a##p = vp_[0]; b##p = vp_[1]; \
    }

#define CONS(kk, aa, bb) { \
    float kv_ = kk; \
    float w_; \
    if (kv_ > mx) { \
        float r_ = __expf(mx - kv_); \
        l *= r_; \
        _Pragma("unroll") for (int j_ = 0; j_ < 16; j_++) acc[j_] *= r_; \
        mx = kv_; w_ = 1.f; \
    } else w_ = __expf(kv_ - mx); \
    l += w_; \
    acc[0]  += bflo(aa.x) * w_; acc[1]  += bfhi(aa.x) * w_; \
    acc[2]  += bflo(aa.y) * w_; acc[3]  += bfhi(aa.y) * w_; \
    acc[4]  += bflo(aa.z) * w_; acc[5]  += bfhi(aa.z) * w_; \
    acc[6]  += bflo(aa.w) * w_; acc[7]  += bfhi(aa.w) * w_; \
    acc[8]  += bflo(bb.x) * w_; acc[9]  += bfhi(bb.x) * w_; \
    acc[10] += bflo(bb.y) * w_; acc[11] += bfhi(bb.y) * w_; \
    acc[12] += bflo(bb.z) * w_; acc[13] += bfhi(bb.z) * w_; \
    acc[14] += bflo(bb.w) * w_; acc[15] += bfhi(bb.w) * w_; \
}

__global__ __launch_bounds__(256) void k_seg(
    const float* __restrict__ ksb, const unsigned short* __restrict__ Vh,
    const int* __restrict__ offs, const int* __restrict__ bsum2,
    const int* __restrict__ csr, const int* __restrict__ order,
    float* __restrict__ out) {
    int t = threadIdx.x;
    int h = t & 7;
    int g = blockIdx.x * 32 + (t >> 3);            // grid 3125*32 = E
    int seg = order[g];
    int beg = offs[seg] + bsum2[seg >> 8];
    int end = (seg + 1 < E) ? (offs[seg + 1] + bsum2[(seg + 1) >> 8]) : M;
    int n = end - beg;

    float acc[16];
#pragma unroll
    for (int j = 0; j < 16; j++) acc[j] = 0.f;
    float l = 0.f, mx = -INFINITY;

    if (n > 0) {
        int s0 = 0, s1 = 0, s2 = 0, s3 = 0, t0 = 0, t1 = 0, t2 = 0, t3 = 0;
        float k0 = 0, k1 = 0, k2 = 0, k3 = 0;
        uint4 a0 = {}, b0 = {}, a1 = {}, b1 = {}, a2 = {}, b2 = {}, a3 = {}, b3 = {};
        s0 = csr[beg];
        if (n > 1) s1 = csr[beg + 1];
        if (n > 2) s2 = csr[beg + 2];
        if (n > 3) s3 = csr[beg + 3];
        ROWL(0, s0, true)
        ROWL(1, s1, n > 1)
        ROWL(2, s2, n > 2)
        ROWL(3, s3, n > 3)
        if (n > 4) t0 = csr[beg + 4];
        if (n > 5) t1 = csr[beg + 5];
        if (n > 6) t2 = csr[beg + 6];
        if (n > 7) t3 = csr[beg + 7];
        int i = 0;
        while (i + 4 <= n) {
            CONS(k0, a0, b0) ROWL(0, t0, i + 4 < n) if (i + 8 < n)  t0 = csr[beg + i + 8];
            CONS(k1, a1, b1) ROWL(1, t1, i + 5 < n) if (i + 9 < n)  t1 = csr[beg + i + 9];
            CONS(k2, a2, b2) ROWL(2, t2, i + 6 < n) if (i + 10 < n) t2 = csr[beg + i + 10];
            CONS(k3, a3, b3) ROWL(3, t3, i + 7 < n) if (i + 11 < n) t3 = csr[beg + i + 11];
            i += 4;
        }
        if (i < n) { CONS(k0, a0, b0) i++; }
        if (i < n) { CONS(k1, a1, b1) i++; }
        if (i < n) { CONS(k2, a2, b2) }
    }
    float inv = 1.0f / (l + 1e-16f);
    float4* op = (float4*)(out + (size_t)seg * 128 + h * 16);
#pragma unroll
    for (int j = 0; j < 4; j++)
        op[j] = make_float4(acc[4 * j] * inv, acc[4 * j + 1] * inv,
                            acc[4 * j + 2] * inv, acc[4 * j + 3] * inv);
}

extern "C" void kernel_launch(void* const* d_in, const int* in_sizes, int n_in,
                              void* d_out, int out_size, void* d_ws, size_t ws_size,
                              hipStream_t stream) {
    const float* edge_attr = (const float*)d_in[0];
    const void*  eei       = d_in[1];
    // d_in[2]=Wq, d_in[3]=bq -- dead: Q cancels in the segment softmax
    const float* Wk = (const float*)d_in[4];
    const float* bk = (const float*)d_in[5];
    const float* Wv = (const float*)d_in[6];
    const float* bv = (const float*)d_in[7];
    const float* Aw = (const float*)d_in[8];
    float* out = (float*)d_out;

    if (ws_size < WS_NEEDED) return;

    char* ws = (char*)d_ws;
    int*   flag   = (int*)(ws + O_FLAG);
    float* weff   = (float*)(ws + O_WEFF);
    float* bkeff  = (float*)(ws + O_BKEFF);
    unsigned short* Bswz = (unsigned short*)(ws + O_BSWZ);
    int*   counts = (int*)(ws + O_COUNTS);
    int*   offs   = (int*)(ws + O_OFFS);
    int*   bsum   = (int*)(ws + O_BSUM);
    int*   bsum2  = (int*)(ws + O_BSUM2);
    int*   binoff = (int*)(ws + O_BINOFF);
    int*   bhist  = (int*)(ws + O_BHIST);
    int*   order  = (int*)(ws + O_ORDER);
    int*   pos    = (int*)(ws + O_POS);
    int*   csr    = (int*)(ws + O_CSR);
    float* ksb    = (float*)(ws + O_KS);
    unsigned short* Vh = (unsigned short*)(ws + O_VH);

    k_prep<<<NBE + 10, 256, 0, stream>>>(Wk, bk, Aw, Wv, (const int*)eei,
                                         counts, flag, weff, bkeff, Bswz);
    k_cp<<<7 * 782, 256, 0, stream>>>(eei, flag, counts, pos, edge_attr,
                                      (const short*)Bswz, bv, weff, bkeff, Vh, ksb);
    k_scanA<<<NBE, 256, 0, stream>>>(counts, offs, bsum, bhist);
    k_scanB<<<1, 512, 0, stream>>>(bsum, bhist, bsum2, binoff, NBE);
    k_fill<<<NBM + NBE, 256, 0, stream>>>(eei, flag, offs, bsum2, pos, csr,
                                          counts, binoff, bhist, order);
    k_seg<<<E / 32, 256, 0, stream>>>(ksb, Vh, offs, bsum2, csr, order, out);
}

// Round 6
// 247.249 us; speedup vs baseline: 2.4692x; 1.3701x over previous
//
#include <hip/hip_runtime.h>
#include <math.h>

static constexpr int E = 100000;   // edges (segments)
static constexpr int M = 1000000;  // edge-edge pairs
static constexpr int NBE = (E + 255) / 256;   // 391
static constexpr int NBM = (M + 255) / 256;   // 3907
static constexpr int NBP = (E + 63) / 64;     // 1563 proj blocks

// ---------------- workspace layout (bytes) ----------------
#define O_FLAG   0
#define O_WEFF   512
#define O_BKEFF  4608
#define O_BSWZ   5120        // 32768 B
#define O_COUNTS 38400       // E ints
#define O_OFFS   438784      // E ints
#define O_BSUM   838784      // 391 ints (pad 2048)
#define O_BSUM2  840832      // 512 ints
#define O_BINOFF 842880      // 256 ints
#define O_BT     843904      // 256 ints
#define O_BHIST  844928      // 391*256 ints = 400384 B
#define O_ORDER  1245312     // E ints
#define O_POS    1645312     // M ints
#define O_CSR    5645312     // M ints
#define O_KS     9645312     // E*8 f32
#define O_VH     12845312    // E*128 bf16 = 25600000 B
#define WS_NEEDED (O_VH + (size_t)E * 128 * 2)

typedef float f32x4 __attribute__((ext_vector_type(4)));
typedef short s16x8 __attribute__((ext_vector_type(8)));

__device__ __forceinline__ unsigned short f2bf(float f) {
    unsigned u = __float_as_uint(f);
    u += 0x7fffu + ((u >> 16) & 1u);
    return (unsigned short)(u >> 16);
}
__device__ __forceinline__ float bflo(unsigned u) { return __uint_as_float(u << 16); }
__device__ __forceinline__ float bfhi(unsigned u) { return __uint_as_float(u & 0xffff0000u); }

// prep: zero counts | weff/bkeff fold | dtype detect | Wv -> MFMA-B bf16 swizzle
__global__ void k_prep(const float* __restrict__ Wk, const float* __restrict__ bk,
                       const float* __restrict__ Aw, const float* __restrict__ Wv,
                       const int* __restrict__ idx32, int* __restrict__ counts,
                       int* __restrict__ flag, float* __restrict__ weff,
                       float* __restrict__ bkeff, unsigned short* __restrict__ Bswz) {
    int bid = blockIdx.x, t = threadIdx.x;
    if (bid < NBE) {
        int i = bid * 256 + t;
        if (i < E) counts[i] = 0;
        return;
    }
    if (bid == NBE) {
        if (t < 128) {
            for (int h = 0; h < 8; h++) {
                float s = 0.f;
                for (int d = 0; d < 16; d++) s += Wk[t * 128 + h * 16 + d] * Aw[d * 8 + h];
                weff[t * 8 + h] = s;
            }
            if (t < 8) {
                float s = 0.f;
                for (int d = 0; d < 16; d++) s += bk[t * 16 + d] * Aw[d * 8 + t];
                bkeff[t] = s;
            }
        }
        return;
    }
    if (bid == NBE + 1) {
        if (t == 0) {
            int z = 0;
            for (int i = 0; i < 64; i++) z += (idx32[2 * i + 1] == 0) ? 1 : 0;
            *flag = (z == 64) ? 1 : 0;
        }
        return;
    }
    int p = (bid - (NBE + 2)) * 256 + t;     // f*64+lane
    int f = p >> 6, lane = p & 63;
    int c = f >> 3, tt = f & 7;
    int quad = lane >> 4, nn = lane & 15;
#pragma unroll
    for (int j = 0; j < 8; j++) {
        int k = c * 32 + quad * 8 + j;
        Bswz[p * 8 + j] = f2bf(Wv[k * 128 + tt * 16 + nn]);
    }
}

// Fused: count+rank atomic pass (5/7 of blocks) interleaved with MFMA projection
// (2/7 of blocks) so streaming/MFMA work overlaps far-atomic latency.
__global__ __launch_bounds__(256) void k_cp(
    const void* __restrict__ idx, const int* __restrict__ flagp,
    int* __restrict__ counts, int* __restrict__ pos,
    const float* __restrict__ A, const short* __restrict__ Bswz,
    const float* __restrict__ bv, const float* __restrict__ weff,
    const float* __restrict__ bkeff, unsigned short* __restrict__ Vh,
    float* __restrict__ ksb) {
    int bid = blockIdx.x, t = threadIdx.x;
    int r = bid % 7;
    if (r < 5) {
        int cid = (bid / 7) * 5 + r;
        if (cid >= NBM) return;
        int m = cid * 256 + t;
        if (m >= M) return;
        int d = (*flagp) ? (int)((const long long*)idx)[M + m] : ((const int*)idx)[M + m];
        pos[m] = atomicAdd(&counts[d], 1);
        return;
    }
    int pid = (bid / 7) * 2 + (r - 5);
    if (pid >= NBP) return;

    __shared__ float we[1024];
    ((float4*)we)[t] = ((const float4*)weff)[t & 255];
    __syncthreads();

    int lane = t & 63, wid = t >> 6;
    int rowbase = pid * 64 + wid * 16;
    int quad = lane >> 4, nn = lane & 15;
    int m = rowbase + nn;
    int mc = (m < E) ? m : (E - 1);

    f32x4 acc[8];
#pragma unroll
    for (int tt = 0; tt < 8; tt++) acc[tt] = (f32x4){0.f, 0.f, 0.f, 0.f};
    float p[8];
#pragma unroll
    for (int h = 0; h < 8; h++) p[h] = 0.f;

#pragma unroll
    for (int c = 0; c < 4; c++) {
        const float4* ap = (const float4*)(A + (size_t)mc * 128 + c * 32 + quad * 8);
        float4 f0 = ap[0], f1 = ap[1];
        float a[8] = {f0.x, f0.y, f0.z, f0.w, f1.x, f1.y, f1.z, f1.w};
#pragma unroll
        for (int j = 0; j < 8; j++) {
            int k = c * 32 + quad * 8 + j;
            float4 w0 = *(const float4*)&we[k * 8];
            float4 w1 = *(const float4*)&we[k * 8 + 4];
            p[0] += a[j] * w0.x; p[1] += a[j] * w0.y;
            p[2] += a[j] * w0.z; p[3] += a[j] * w0.w;
            p[4] += a[j] * w1.x; p[5] += a[j] * w1.y;
            p[6] += a[j] * w1.z; p[7] += a[j] * w1.w;
        }
        s16x8 afrag;
#pragma unroll
        for (int j = 0; j < 8; j++) afrag[j] = (short)f2bf(a[j]);
#pragma unroll
        for (int tt = 0; tt < 8; tt++) {
            s16x8 bfrag = *(const s16x8*)(Bswz + (((c * 8 + tt) * 64 + lane) << 3));
            acc[tt] = __builtin_amdgcn_mfma_f32_16x16x32_bf16(afrag, bfrag, acc[tt], 0, 0, 0);
        }
    }
#pragma unroll
    for (int off = 16; off <= 32; off <<= 1)
#pragma unroll
        for (int h = 0; h < 8; h++) p[h] += __shfl_xor(p[h], off, 64);
    if (quad == 0 && m < E) {
        float4* op = (float4*)(ksb + (size_t)m * 8);
        op[0] = make_float4(p[0] + bkeff[0], p[1] + bkeff[1], p[2] + bkeff[2], p[3] + bkeff[3]);
        op[1] = make_float4(p[4] + bkeff[4], p[5] + bkeff[5], p[6] + bkeff[6], p[7] + bkeff[7]);
    }
#pragma unroll
    for (int tt = 0; tt < 8; tt++) {
        float bvc = bv[tt * 16 + nn];
#pragma unroll
        for (int rr = 0; rr < 4; rr++) {
            int row = rowbase + quad * 4 + rr;
            if (row < E)
                Vh[(size_t)row * 128 + tt * 16 + nn] = f2bf(acc[tt][rr] + bvc);
        }
    }
}

// scanA: per-256-block exclusive scan of counts + per-block 256-bin length histogram
__global__ void k_scanA(const int* __restrict__ counts, int* __restrict__ offs,
                        int* __restrict__ bsum, int* __restrict__ bhist) {
    __shared__ int sm[256];
    __shared__ int hist[256];
    int tid = threadIdx.x;
    int i = blockIdx.x * 256 + tid;
    int v = (i < E) ? counts[i] : 0;
    hist[tid] = 0;
    sm[tid] = v;
    __syncthreads();
    if (i < E) atomicAdd(&hist[v > 255 ? 255 : v], 1);
    for (int off = 1; off < 256; off <<= 1) {
        int add = (tid >= off) ? sm[tid - off] : 0;
        __syncthreads();
        sm[tid] += add;
        __syncthreads();
    }
    if (i < E) offs[i] = sm[tid] - v;
    if (tid == 255) bsum[blockIdx.x] = sm[255];
    bhist[blockIdx.x * 256 + tid] = hist[tid];
}

// scanBcol: 256 blocks, one per length-bin. Block-scan the 391-long column of
// bhist (per-block histogram counts) into exclusive prefixes; total -> bt[bin].
__global__ void k_scanBcol(int* __restrict__ bhist, int* __restrict__ bt) {
    __shared__ int sm[512];
    int b = blockIdx.x, t = threadIdx.x;
    int v = (t < NBE) ? bhist[t * 256 + b] : 0;
    sm[t] = v;
    __syncthreads();
    for (int off = 1; off < 512; off <<= 1) {
        int add = (t >= off) ? sm[t - off] : 0;
        __syncthreads();
        sm[t] += add;
        __syncthreads();
    }
    if (t < NBE) bhist[t * 256 + b] = sm[t] - v;
    if (t == 511) bt[b] = sm[511];
}

// scanB2: scan block sums (bsum2) + descending-bin exclusive offsets (binoff).
__global__ void k_scanB2(const int* __restrict__ bsum, const int* __restrict__ bt,
                         int* __restrict__ bsum2, int* __restrict__ binoff, int nb) {
    __shared__ int sm[512];
    __shared__ int s2[256];
    int tid = threadIdx.x;
    int v = (tid < nb) ? bsum[tid] : 0;
    sm[tid] = v;
    __syncthreads();
    for (int off = 1; off < 512; off <<= 1) {
        int add = (tid >= off) ? sm[tid - off] : 0;
        __syncthreads();
        sm[tid] += add;
        __syncthreads();
    }
    bsum2[tid] = sm[tid] - v;
    if (tid < 256) s2[tid] = bt[255 - tid];
    __syncthreads();
    for (int off = 1; off < 256; off <<= 1) {
        int add = (tid < 256 && tid >= off) ? s2[tid - off] : 0;
        __syncthreads();
        if (tid < 256) s2[tid] += add;
        __syncthreads();
    }
    if (tid < 256) binoff[tid] = s2[255 - tid] - bt[tid];  // sum of bt[b'>tid]
}

// Fused: atomic-free CSR fill + order scatter (grouped by n desc, LDS-rank only)
__global__ void k_fill(const void* __restrict__ idx, const int* __restrict__ flagp,
                       const int* __restrict__ offs, const int* __restrict__ bsum2,
                       const int* __restrict__ pos, int* __restrict__ csr,
                       const int* __restrict__ counts, const int* __restrict__ binoff,
                       const int* __restrict__ bhist, int* __restrict__ order) {
    int bid = blockIdx.x, t = threadIdx.x;
    if (bid < NBM) {
        int m = bid * 256 + t;
        if (m >= M) return;
        int s, d;
        if (*flagp) {
            const long long* p = (const long long*)idx;
            s = (int)p[m]; d = (int)p[M + m];
        } else {
            const int* p = (const int*)idx;
            s = p[m]; d = p[M + m];
        }
        csr[offs[d] + bsum2[d >> 8] + pos[m]] = s;
        return;
    }
    __shared__ int lh[256];
    int blk = bid - NBM;
    int i = blk * 256 + t;
    lh[t] = 0;
    __syncthreads();
    if (i >= E) return;
    int n = counts[i];
    if (n > 255) n = 255;
    int lr = atomicAdd(&lh[n], 1);            // LDS atomic: intra-block rank
    order[binoff[n] + bhist[blk * 256 + n] + lr] = i;
}

// One lane per (segment, head); segments grouped by identical n (via order[]).
// Online softmax, 4-deep rotating prefetch: csr 8 ahead, ks+Vh rows 4 ahead.
#define ROWL(p, sidx, cond) \
    if (cond) { \
        k##p = ksb[(size_t)(sidx) * 8 + h]; \
        const uint4* vp_ = (const uint4*)(Vh + (size_t)(sidx) * 128 + (h << 4)); \
        a##p = vp_[0]; b##p = vp_[1]; \
    }

#define CONS(kk, aa, bb) { \
    float kv_ = kk; \
    float w_; \
    if (kv_ > mx) { \
        float r_ = __expf(mx - kv_); \
        l *= r_; \
        _Pragma("unroll") for (int j_ = 0; j_ < 16; j_++) acc[j_] *= r_; \
        mx = kv_; w_ = 1.f; \
    } else w_ = __expf(kv_ - mx); \
    l += w_; \
    acc[0]  += bflo(aa.x) * w_; acc[1]  += bfhi(aa.x) * w_; \
    acc[2]  += bflo(aa.y) * w_; acc[3]  += bfhi(aa.y) * w_; \
    acc[4]  += bflo(aa.z) * w_; acc[5]  += bfhi(aa.z) * w_; \
    acc[6]  += bflo(aa.w) * w_; acc[7]  += bfhi(aa.w) * w_; \
    acc[8]  += bflo(bb.x) * w_; acc[9]  += bfhi(bb.x) * w_; \
    acc[10] += bflo(bb.y) * w_; acc[11] += bfhi(bb.y) * w_; \
    acc[12] += bflo(bb.z) * w_; acc[13] += bfhi(bb.z) * w_; \
    acc[14] += bflo(bb.w) * w_; acc[15] += bfhi(bb.w) * w_; \
}

__global__ __launch_bounds__(256) void k_seg(
    const float* __restrict__ ksb, const unsigned short* __restrict__ Vh,
    const int* __restrict__ offs, const int* __restrict__ bsum2,
    const int* __restrict__ csr, const int* __restrict__ order,
    float* __restrict__ out) {
    int t = threadIdx.x;
    int h = t & 7;
    int g = blockIdx.x * 32 + (t >> 3);            // grid 3125*32 = E
    int seg = order[g];
    int beg = offs[seg] + bsum2[seg >> 8];
    int end = (seg + 1 < E) ? (offs[seg + 1] + bsum2[(seg + 1) >> 8]) : M;
    int n = end - beg;

    float acc[16];
#pragma unroll
    for (int j = 0; j < 16; j++) acc[j] = 0.f;
    float l = 0.f, mx = -INFINITY;

    if (n > 0) {
        int s0 = 0, s1 = 0, s2 = 0, s3 = 0, t0 = 0, t1 = 0, t2 = 0, t3 = 0;
        float k0 = 0, k1 = 0, k2 = 0, k3 = 0;
        uint4 a0 = {}, b0 = {}, a1 = {}, b1 = {}, a2 = {}, b2 = {}, a3 = {}, b3 = {};
        s0 = csr[beg];
        if (n > 1) s1 = csr[beg + 1];
        if (n > 2) s2 = csr[beg + 2];
        if (n > 3) s3 = csr[beg + 3];
        ROWL(0, s0, true)
        ROWL(1, s1, n > 1)
        ROWL(2, s2, n > 2)
        ROWL(3, s3, n > 3)
        if (n > 4) t0 = csr[beg + 4];
        if (n > 5) t1 = csr[beg + 5];
        if (n > 6) t2 = csr[beg + 6];
        if (n > 7) t3 = csr[beg + 7];
        int i = 0;
        while (i + 4 <= n) {
            CONS(k0, a0, b0) ROWL(0, t0, i + 4 < n) if (i + 8 < n)  t0 = csr[beg + i + 8];
            CONS(k1, a1, b1) ROWL(1, t1, i + 5 < n) if (i + 9 < n)  t1 = csr[beg + i + 9];
            CONS(k2, a2, b2) ROWL(2, t2, i + 6 < n) if (i + 10 < n) t2 = csr[beg + i + 10];
            CONS(k3, a3, b3) ROWL(3, t3, i + 7 < n) if (i + 11 < n) t3 = csr[beg + i + 11];
            i += 4;
        }
        if (i < n) { CONS(k0, a0, b0) i++; }
        if (i < n) { CONS(k1, a1, b1) i++; }
        if (i < n) { CONS(k2, a2, b2) }
    }
    float inv = 1.0f / (l + 1e-16f);
    float4* op = (float4*)(out + (size_t)seg * 128 + h * 16);
#pragma unroll
    for (int j = 0; j < 4; j++)
        op[j] = make_float4(acc[4 * j] * inv, acc[4 * j + 1] * inv,
                            acc[4 * j + 2] * inv, acc[4 * j + 3] * inv);
}

extern "C" void kernel_launch(void* const* d_in, const int* in_sizes, int n_in,
                              void* d_out, int out_size, void* d_ws, size_t ws_size,
                              hipStream_t stream) {
    const float* edge_attr = (const float*)d_in[0];
    const void*  eei       = d_in[1];
    // d_in[2]=Wq, d_in[3]=bq -- dead: Q cancels in the segment softmax
    const float* Wk = (const float*)d_in[4];
    const float* bk = (const float*)d_in[5];
    const float* Wv = (const float*)d_in[6];
    const float* bv = (const float*)d_in[7];
    const float* Aw = (const float*)d_in[8];
    float* out = (float*)d_out;

    if (ws_size < WS_NEEDED) return;

    char* ws = (char*)d_ws;
    int*   flag   = (int*)(ws + O_FLAG);
    float* weff   = (float*)(ws + O_WEFF);
    float* bkeff  = (float*)(ws + O_BKEFF);
    unsigned short* Bswz = (unsigned short*)(ws + O_BSWZ);
    int*   counts = (int*)(ws + O_COUNTS);
    int*   offs   = (int*)(ws + O_OFFS);
    int*   bsum   = (int*)(ws + O_BSUM);
    int*   bsum2  = (int*)(ws + O_BSUM2);
    int*   binoff = (int*)(ws + O_BINOFF);
    int*   bt     = (int*)(ws + O_BT);
    int*   bhist  = (int*)(ws + O_BHIST);
    int*   order  = (int*)(ws + O_ORDER);
    int*   pos    = (int*)(ws + O_POS);
    int*   csr    = (int*)(ws + O_CSR);
    float* ksb    = (float*)(ws + O_KS);
    unsigned short* Vh = (unsigned short*)(ws + O_VH);

    k_prep<<<NBE + 10, 256, 0, stream>>>(Wk, bk, Aw, Wv, (const int*)eei,
                                         counts, flag, weff, bkeff, Bswz);
    k_cp<<<7 * 782, 256, 0, stream>>>(eei, flag, counts, pos, edge_attr,
                                      (const short*)Bswz, bv, weff, bkeff, Vh, ksb);
    k_scanA<<<NBE, 256, 0, stream>>>(counts, offs, bsum, bhist);
    k_scanBcol<<<256, 512, 0, stream>>>(bhist, bt);
    k_scanB2<<<1, 512, 0, stream>>>(bsum, bt, bsum2, binoff, NBE);
    k_fill<<<NBM + NBE, 256, 0, stream>>>(eei, flag, offs, bsum2, pos, csr,
                                          counts, binoff, bhist, order);
    k_seg<<<E / 32, 256, 0, stream>>>(ksb, Vh, offs, bsum2, csr, order, out);
}